// Round 4
// baseline (93.612 us; speedup 1.0000x reference)
//
#include <hip/hip_runtime.h>
#include <hip/hip_bf16.h>
#include <stdint.h>

// ---- types -----------------------------------------------------------------
typedef __bf16 bf16x8 __attribute__((ext_vector_type(8)));
typedef float  f32x4  __attribute__((ext_vector_type(4)));
typedef __attribute__((address_space(1))) const void* gptr_t;
typedef __attribute__((address_space(3))) void*       sptr_t;

#define B_ROWS 8192
#define C_CLS  1000
#define C_PAD  1024
#define P_DIM  512
#define EPS    1e-10f

// ---- workspace layout (bytes) ----------------------------------------------
// [0,            1048576)  means_bf16  [1024][512] bf16  (rows >=1000 zeroed)
// [1048576,      1052672)  m_sq        [1024] f32
// [1052672,      9441280)  xn_bf16     [8192][512] bf16
// [9441280,      9474048)  x_sq        [8192] f32
#define WS_MEANS_BF 0
#define WS_MSQ      1048576
#define WS_XN_BF    1052672
#define WS_XSQ      9441280

__device__ __forceinline__ float dot8(float4 a, float4 b) {
    return a.x * a.x + a.y * a.y + a.z * a.z + a.w * a.w
         + b.x * b.x + b.y * b.y + b.z * b.z + b.w * b.w;
}

// ---- kernel 1 (fused prep): blocks 0..2047 -> x rows; 2048..2303 -> means ---
// (identical to R1 best. R2 showed fusing this into the gemm regresses 17 us.)
__global__ __launch_bounds__(256) void prep_k(const float* __restrict__ x,
                                              const float* __restrict__ means,
                                              __hip_bfloat16* __restrict__ means_bf,
                                              float* __restrict__ m_sq,
                                              __hip_bfloat16* __restrict__ xn_bf,
                                              float* __restrict__ x_sq) {
    const int w = threadIdx.x >> 6;
    const int l = threadIdx.x & 63;
    const int bid = blockIdx.x;

    if (bid < B_ROWS / 4) {
        // ---- x row: one wave per row
        const int row = bid * 4 + w;
        const float4* m0 = (const float4*)means;   // scale source, L2-hot
        float4 ma = m0[l * 2];
        float4 mb = m0[l * 2 + 1];
        float ms = dot8(ma, mb);
        const float4* xr = (const float4*)(x + (size_t)row * P_DIM);
        float4 a = xr[l * 2];
        float4 b = xr[l * 2 + 1];
        float s = dot8(a, b);
        #pragma unroll
        for (int off = 32; off > 0; off >>= 1) {
            ms += __shfl_down(ms, off);
            s  += __shfl_down(s, off);
        }
        ms = __shfl(ms, 0);
        s  = __shfl(s, 0);
        float scale = sqrtf(ms);               // ||means[0]||
        float norm  = sqrtf(s);
        float sc    = scale / (norm + EPS);
        alignas(16) __hip_bfloat16 tmp[8];
        tmp[0] = __float2bfloat16(a.x * sc); tmp[1] = __float2bfloat16(a.y * sc);
        tmp[2] = __float2bfloat16(a.z * sc); tmp[3] = __float2bfloat16(a.w * sc);
        tmp[4] = __float2bfloat16(b.x * sc); tmp[5] = __float2bfloat16(b.y * sc);
        tmp[6] = __float2bfloat16(b.z * sc); tmp[7] = __float2bfloat16(b.w * sc);
        *(uint4*)(xn_bf + (size_t)row * P_DIM + l * 8) = *(const uint4*)tmp;
        if (l == 0) {
            float sn = sc * norm;              // ||xn|| as the reference computes it
            x_sq[row] = sn * sn;
        }
    } else {
        // ---- means row: one wave per class (padded to 1024)
        const int c = (bid - B_ROWS / 4) * 4 + w;
        if (c < C_CLS) {
            const float4* mr = (const float4*)(means + (size_t)c * P_DIM);
            float4 a = mr[l * 2];
            float4 b = mr[l * 2 + 1];
            float s = dot8(a, b);
            alignas(16) __hip_bfloat16 tmp[8];
            tmp[0] = __float2bfloat16(a.x); tmp[1] = __float2bfloat16(a.y);
            tmp[2] = __float2bfloat16(a.z); tmp[3] = __float2bfloat16(a.w);
            tmp[4] = __float2bfloat16(b.x); tmp[5] = __float2bfloat16(b.y);
            tmp[6] = __float2bfloat16(b.z); tmp[7] = __float2bfloat16(b.w);
            *(uint4*)(means_bf + (size_t)c * P_DIM + l * 8) = *(const uint4*)tmp;
            #pragma unroll
            for (int off = 32; off > 0; off >>= 1) s += __shfl_down(s, off);
            if (l == 0) m_sq[c] = s;
        } else {
            uint4 z = {0u, 0u, 0u, 0u};
            *(uint4*)(means_bf + (size_t)c * P_DIM + l * 8) = z;
            if (l == 0) m_sq[c] = 0.0f;
        }
    }
}

// ---- kernel 2: logits = 2*(xn @ means^T) - x_sq - m_sq ---------------------
// R4: m97 structure at 128x128 tile, BK=64, SINGLE-buffered, plain
// __syncthreads (R3's explicit pipeline regressed +3.4 us -- guide m99-m141).
// 4 waves in 2x2; wave (wr,wc) computes a 64x64 sub-tile via acc[4][4] of
// 16x16x32 MFMA: 32 MFMA per 16 ds_read_b128 per K-step (2x the arithmetic
// density of the R1 64x128 tile -- the ladder's biggest lever, m93/m103).
// Grid 512 = 64 brow x 8 bcol = exactly 2 blocks/CU, one pass.
// XCD remap (T1): per-XCD set = 1 MB A-slice + 1 MB B, L2-resident.
// LDS 32 KB: A[128][128B] @0, B[128][128B] @16384; R1-proven XOR swizzle
// (source chunk^(row&7), read kb^((m16&7)<<4)) -- read quad distribution
// (s*4+q)^(m16&7) = 8 lanes/quad = conflict-free b128 minimum.
__global__ __launch_bounds__(256, 2) void gemm_k(const __hip_bfloat16* __restrict__ A,   // xn   [8192][512]
                                                 const __hip_bfloat16* __restrict__ B,   // means[1024][512]
                                                 const float* __restrict__ x_sq,
                                                 const float* __restrict__ m_sq,
                                                 float* __restrict__ out) {
    __shared__ alignas(16) char lds[32768];
    const int t   = threadIdx.x;
    const int w   = t >> 6;         // wave 0..3
    const int l   = t & 63;
    const int q   = l >> 4;         // quad 0..3
    const int m16 = l & 15;
    const int wr  = w >> 1;         // wave row 0..1 (64-row halves)
    const int wc  = w & 1;          // wave col 0..1 (64-col halves)

    // XCD-aware remap: n%8 = XCD; each XCD owns 8 consecutive brows x all bcols.
    const int n_blk  = blockIdx.x;            // 0..511
    const int xcd    = n_blk & 7;
    const int within = n_blk >> 3;            // 0..63
    const int brow   = xcd * 8 + (within & 7);     // 0..63 (128-row tiles)
    const int bcol   = within >> 3;                // 0..7  (128-col tiles)

    f32x4 acc[4][4];
    #pragma unroll
    for (int i = 0; i < 4; ++i)
        #pragma unroll
        for (int j = 0; j < 4; ++j) {
            f32x4 z = {0.f, 0.f, 0.f, 0.f};
            acc[i][j] = z;
        }

    const char* Abase = (const char*)A + (size_t)(brow * 128) * (P_DIM * 2);
    const char* Bbase = (const char*)B + (size_t)(bcol * 128) * (P_DIM * 2);

    const int swz = (m16 & 7) << 4;     // read-side XOR, uniform across frags

    for (int k0 = 0; k0 < P_DIM; k0 += 64) {
        // ---- stage 32 KB: A tile 16 KB (rounds 0-3) + B tile 16 KB (4-7).
        // LDS dest wave-uniform + lane*16 (linear). Global source address is
        // inverse-swizzled: LDS chunk c of row holds global chunk c^(row&7).
        #pragma unroll
        for (int r = 0; r < 8; ++r) {
            const int wbase = r * 4096 + w * 1024;       // wave-uniform, 0..32K
            const int o     = (wbase & 16383) + l * 16;  // offset within region
            const int row   = o >> 7;                    // 0..127
            const int c     = (o >> 4) & 7;
            const char* g;
            if (r < 4) {
                g = Abase + (size_t)row * (P_DIM * 2) + k0 * 2 + ((c ^ (row & 7)) << 4);
            } else {
                g = Bbase + (size_t)row * (P_DIM * 2) + k0 * 2 + ((c ^ (row & 7)) << 4);
            }
            __builtin_amdgcn_global_load_lds((gptr_t)g, (sptr_t)(lds + wbase), 16, 0, 0);
        }
        __syncthreads();

        // ---- two K=32 mfma sub-steps over the staged BK=64 tile
        #pragma unroll
        for (int s = 0; s < 2; ++s) {
            const int kb = s * 64 + q * 16;      // byte offset within 128-B row
            bf16x8 af[4], bfr[4];
            #pragma unroll
            for (int i = 0; i < 4; ++i) {
                const int m = wr * 64 + i * 16 + m16;    // m&7 == m16&7
                af[i] = *(const bf16x8*)(lds + m * 128 + (kb ^ swz));
            }
            #pragma unroll
            for (int j = 0; j < 4; ++j) {
                const int nn = wc * 64 + j * 16 + m16;   // nn&7 == m16&7
                bfr[j] = *(const bf16x8*)(lds + 16384 + nn * 128 + (kb ^ swz));
            }
            #pragma unroll
            for (int i = 0; i < 4; ++i)
                #pragma unroll
                for (int j = 0; j < 4; ++j)
                    acc[i][j] = __builtin_amdgcn_mfma_f32_16x16x32_bf16(af[i], bfr[j], acc[i][j], 0, 0, 0);
        }
        __syncthreads();
    }

    // ---- epilogue: out = 2*cross - x_sq[row] - m_sq[col]
    // C/D layout: col = lane&15, row = quad*4 + reg [verified m89/m91 + R2 pass]
    const int rowbase = brow * 128 + wr * 64;
    const int colbase = bcol * 128 + wc * 64;
    float msq[4];
    #pragma unroll
    for (int j = 0; j < 4; ++j) {
        const int col = colbase + j * 16 + m16;
        msq[j] = (col < C_CLS) ? m_sq[col] : 0.0f;
    }
    #pragma unroll
    for (int i = 0; i < 4; ++i) {
        #pragma unroll
        for (int reg = 0; reg < 4; ++reg) {
            const int row = rowbase + i * 16 + q * 4 + reg;
            const float xsq = x_sq[row];
            #pragma unroll
            for (int j = 0; j < 4; ++j) {
                const int col = colbase + j * 16 + m16;
                if (col < C_CLS) {
                    out[(size_t)row * C_CLS + col] = 2.0f * acc[i][j][reg] - xsq - msq[j];
                }
            }
        }
    }
}

// ---- launch ----------------------------------------------------------------
extern "C" void kernel_launch(void* const* d_in, const int* in_sizes, int n_in,
                              void* d_out, int out_size, void* d_ws, size_t ws_size,
                              hipStream_t stream) {
    const float* x     = (const float*)d_in[0];   // [8192][512]
    const float* means = (const float*)d_in[1];   // [1000][512]
    float* out = (float*)d_out;                   // [8192][1000]
    char* ws = (char*)d_ws;

    __hip_bfloat16* means_bf = (__hip_bfloat16*)(ws + WS_MEANS_BF);
    float*          m_sq     = (float*)(ws + WS_MSQ);
    __hip_bfloat16* xn_bf    = (__hip_bfloat16*)(ws + WS_XN_BF);
    float*          x_sq     = (float*)(ws + WS_XSQ);

    prep_k<<<B_ROWS / 4 + C_PAD / 4, 256, 0, stream>>>(x, means, means_bf, m_sq, xn_bf, x_sq);
    gemm_k<<<512, 256, 0, stream>>>(xn_bf, means_bf, x_sq, m_sq, out);
}

// Round 5
// 89.133 us; speedup vs baseline: 1.0502x; 1.0502x over previous
//
#include <hip/hip_runtime.h>
#include <hip/hip_bf16.h>
#include <stdint.h>

// ---- types -----------------------------------------------------------------
typedef __bf16 bf16x8 __attribute__((ext_vector_type(8)));
typedef float  f32x4  __attribute__((ext_vector_type(4)));
typedef __attribute__((address_space(1))) const void* gptr_t;
typedef __attribute__((address_space(3))) void*       sptr_t;

#define B_ROWS 8192
#define C_CLS  1000
#define C_PAD  1024
#define P_DIM  512
#define EPS    1e-10f

// ---- workspace layout (bytes) ----------------------------------------------
// [0,            1048576)  means_bf16  [1024][512] bf16  (rows >=1000 zeroed)
// [1048576,      1052672)  m_sq        [1024] f32
// [1052672,      9441280)  xn_bf16     [8192][512] bf16
// [9441280,      9474048)  x_sq        [8192] f32
#define WS_MEANS_BF 0
#define WS_MSQ      1048576
#define WS_XN_BF    1052672
#define WS_XSQ      9441280

__device__ __forceinline__ float dot8(float4 a, float4 b) {
    return a.x * a.x + a.y * a.y + a.z * a.z + a.w * a.w
         + b.x * b.x + b.y * b.y + b.z * b.z + b.w * b.w;
}

// ---- kernel 1 (fused prep): blocks 0..2047 -> x rows; 2048..2303 -> means ---
// (identical to R1 best. R2 showed fusing this into the gemm regresses 17 us.)
__global__ __launch_bounds__(256) void prep_k(const float* __restrict__ x,
                                              const float* __restrict__ means,
                                              __hip_bfloat16* __restrict__ means_bf,
                                              float* __restrict__ m_sq,
                                              __hip_bfloat16* __restrict__ xn_bf,
                                              float* __restrict__ x_sq) {
    const int w = threadIdx.x >> 6;
    const int l = threadIdx.x & 63;
    const int bid = blockIdx.x;

    if (bid < B_ROWS / 4) {
        // ---- x row: one wave per row
        const int row = bid * 4 + w;
        const float4* m0 = (const float4*)means;   // scale source, L2-hot
        float4 ma = m0[l * 2];
        float4 mb = m0[l * 2 + 1];
        float ms = dot8(ma, mb);
        const float4* xr = (const float4*)(x + (size_t)row * P_DIM);
        float4 a = xr[l * 2];
        float4 b = xr[l * 2 + 1];
        float s = dot8(a, b);
        #pragma unroll
        for (int off = 32; off > 0; off >>= 1) {
            ms += __shfl_down(ms, off);
            s  += __shfl_down(s, off);
        }
        ms = __shfl(ms, 0);
        s  = __shfl(s, 0);
        float scale = sqrtf(ms);               // ||means[0]||
        float norm  = sqrtf(s);
        float sc    = scale / (norm + EPS);
        alignas(16) __hip_bfloat16 tmp[8];
        tmp[0] = __float2bfloat16(a.x * sc); tmp[1] = __float2bfloat16(a.y * sc);
        tmp[2] = __float2bfloat16(a.z * sc); tmp[3] = __float2bfloat16(a.w * sc);
        tmp[4] = __float2bfloat16(b.x * sc); tmp[5] = __float2bfloat16(b.y * sc);
        tmp[6] = __float2bfloat16(b.z * sc); tmp[7] = __float2bfloat16(b.w * sc);
        *(uint4*)(xn_bf + (size_t)row * P_DIM + l * 8) = *(const uint4*)tmp;
        if (l == 0) {
            float sn = sc * norm;              // ||xn|| as the reference computes it
            x_sq[row] = sn * sn;
        }
    } else {
        // ---- means row: one wave per class (padded to 1024)
        const int c = (bid - B_ROWS / 4) * 4 + w;
        if (c < C_CLS) {
            const float4* mr = (const float4*)(means + (size_t)c * P_DIM);
            float4 a = mr[l * 2];
            float4 b = mr[l * 2 + 1];
            float s = dot8(a, b);
            alignas(16) __hip_bfloat16 tmp[8];
            tmp[0] = __float2bfloat16(a.x); tmp[1] = __float2bfloat16(a.y);
            tmp[2] = __float2bfloat16(a.z); tmp[3] = __float2bfloat16(a.w);
            tmp[4] = __float2bfloat16(b.x); tmp[5] = __float2bfloat16(b.y);
            tmp[6] = __float2bfloat16(b.z); tmp[7] = __float2bfloat16(b.w);
            *(uint4*)(means_bf + (size_t)c * P_DIM + l * 8) = *(const uint4*)tmp;
            #pragma unroll
            for (int off = 32; off > 0; off >>= 1) s += __shfl_down(s, off);
            if (l == 0) m_sq[c] = s;
        } else {
            uint4 z = {0u, 0u, 0u, 0u};
            *(uint4*)(means_bf + (size_t)c * P_DIM + l * 8) = z;
            if (l == 0) m_sq[c] = 0.0f;
        }
    }
}

// ---- kernel 2: logits = 2*(xn @ means^T) - x_sq - m_sq ---------------------
// R5: 128x128 tile with EIGHT waves (512 threads) -- R4 showed 128x128 with
// 4 waves halves occupancy (8 waves/CU) and regresses; this keeps R1's
// 16 waves/CU (2 blocks/CU x 8 waves) while doubling arithmetic density
// (B-frags shared across wave rows: 16 MFMA per 6 ds_read_b128 per wave-K-step
// vs R1's 16 per 12). Same proven 2-barrier schedule (R3's explicit pipeline
// regressed), same glload_lds staging, same XOR swizzle, same XCD remap.
// Wave (wr=w>>2, wc=w&3) owns a 64x32 sub-tile: acc[4][2], ~56 live VGPR,
// fits the 128-VGPR budget for 4 waves/SIMD (launch_bounds(512,4)).
// Grid 512 = 64 brow x 8 bcol = exactly 2 blocks/CU, one pass.
// LDS 32 KB: A[128][128B] @0, B[128][128B] @16384; 64 KB/CU total.
// Swizzle bank check (ds_read): chunk = (s*4+q)^(m16&7) -> each of 8 chunk
// slots gets 8 lanes = conflict-free b128 minimum (same derivation as R4).
__global__ __launch_bounds__(512, 4) void gemm_k(const __hip_bfloat16* __restrict__ A,   // xn   [8192][512]
                                                 const __hip_bfloat16* __restrict__ B,   // means[1024][512]
                                                 const float* __restrict__ x_sq,
                                                 const float* __restrict__ m_sq,
                                                 float* __restrict__ out) {
    __shared__ alignas(16) char lds[32768];
    const int t   = threadIdx.x;
    const int w   = t >> 6;         // wave 0..7
    const int l   = t & 63;
    const int q   = l >> 4;         // quad 0..3
    const int m16 = l & 15;
    const int wr  = w >> 2;         // wave row 0..1 (64-row halves)
    const int wc  = w & 3;          // wave col 0..3 (32-col quarters)

    // XCD-aware remap: n%8 = XCD; each XCD owns 8 consecutive brows x all bcols.
    const int n_blk  = blockIdx.x;            // 0..511
    const int xcd    = n_blk & 7;
    const int within = n_blk >> 3;            // 0..63
    const int brow   = xcd * 8 + (within & 7);     // 0..63 (128-row tiles)
    const int bcol   = within >> 3;                // 0..7  (128-col tiles)

    f32x4 acc[4][2];
    #pragma unroll
    for (int i = 0; i < 4; ++i)
        #pragma unroll
        for (int j = 0; j < 2; ++j) {
            f32x4 z = {0.f, 0.f, 0.f, 0.f};
            acc[i][j] = z;
        }

    const char* Abase = (const char*)A + (size_t)(brow * 128) * (P_DIM * 2);
    const char* Bbase = (const char*)B + (size_t)(bcol * 128) * (P_DIM * 2);

    const int swz = (m16 & 7) << 4;     // read-side XOR, uniform across frags

    for (int k0 = 0; k0 < P_DIM; k0 += 64) {
        // ---- stage 32 KB in 4 rounds of 8 KB (512 threads x 16 B):
        // rounds 0-1 -> A region, 2-3 -> B region. LDS dest is wave-uniform
        // base + lane*16 (linear); global source is inverse-swizzled
        // (chunk c of row holds global chunk c^(row&7)).
        #pragma unroll
        for (int r = 0; r < 4; ++r) {
            const int o   = (r & 1) * 8192 + w * 1024 + l * 16;   // 0..16384 in region
            const int row = o >> 7;                               // 0..127
            const int c   = (o >> 4) & 7;
            const char* gb = (r < 2) ? Abase : Bbase;
            const char* g  = gb + (size_t)row * (P_DIM * 2) + k0 * 2 + ((c ^ (row & 7)) << 4);
            char* dst = lds + ((r < 2) ? 0 : 16384) + (r & 1) * 8192 + w * 1024;
            __builtin_amdgcn_global_load_lds((gptr_t)g, (sptr_t)dst, 16, 0, 0);
        }
        __syncthreads();

        // ---- two K=32 mfma sub-steps over the staged BK=64 tile
        #pragma unroll
        for (int s = 0; s < 2; ++s) {
            const int kb = s * 64 + q * 16;      // byte offset within 128-B row
            bf16x8 af[4], bfr[2];
            #pragma unroll
            for (int i = 0; i < 4; ++i) {
                const int m = wr * 64 + i * 16 + m16;    // m&7 == m16&7
                af[i] = *(const bf16x8*)(lds + m * 128 + (kb ^ swz));
            }
            #pragma unroll
            for (int j = 0; j < 2; ++j) {
                const int nn = wc * 32 + j * 16 + m16;   // nn&7 == m16&7
                bfr[j] = *(const bf16x8*)(lds + 16384 + nn * 128 + (kb ^ swz));
            }
            #pragma unroll
            for (int i = 0; i < 4; ++i)
                #pragma unroll
                for (int j = 0; j < 2; ++j)
                    acc[i][j] = __builtin_amdgcn_mfma_f32_16x16x32_bf16(af[i], bfr[j], acc[i][j], 0, 0, 0);
        }
        __syncthreads();
    }

    // ---- epilogue: out = 2*cross - x_sq[row] - m_sq[col]
    // C/D layout: col = lane&15, row = quad*4 + reg [verified m89/m91 + R2 pass]
    const int rowbase = brow * 128 + wr * 64;
    const int colbase = bcol * 128 + wc * 32;
    float msq[2];
    #pragma unroll
    for (int j = 0; j < 2; ++j) {
        const int col = colbase + j * 16 + m16;
        msq[j] = (col < C_CLS) ? m_sq[col] : 0.0f;
    }
    #pragma unroll
    for (int i = 0; i < 4; ++i) {
        #pragma unroll
        for (int reg = 0; reg < 4; ++reg) {
            const int row = rowbase + i * 16 + q * 4 + reg;
            const float xsq = x_sq[row];
            #pragma unroll
            for (int j = 0; j < 2; ++j) {
                const int col = colbase + j * 16 + m16;
                if (col < C_CLS) {
                    out[(size_t)row * C_CLS + col] = 2.0f * acc[i][j][reg] - xsq - msq[j];
                }
            }
        }
    }
}

// ---- launch ----------------------------------------------------------------
extern "C" void kernel_launch(void* const* d_in, const int* in_sizes, int n_in,
                              void* d_out, int out_size, void* d_ws, size_t ws_size,
                              hipStream_t stream) {
    const float* x     = (const float*)d_in[0];   // [8192][512]
    const float* means = (const float*)d_in[1];   // [1000][512]
    float* out = (float*)d_out;                   // [8192][1000]
    char* ws = (char*)d_ws;

    __hip_bfloat16* means_bf = (__hip_bfloat16*)(ws + WS_MEANS_BF);
    float*          m_sq     = (float*)(ws + WS_MSQ);
    __hip_bfloat16* xn_bf    = (__hip_bfloat16*)(ws + WS_XN_BF);
    float*          x_sq     = (float*)(ws + WS_XSQ);

    prep_k<<<B_ROWS / 4 + C_PAD / 4, 256, 0, stream>>>(x, means, means_bf, m_sq, xn_bf, x_sq);
    gemm_k<<<512, 512, 0, stream>>>(xn_bf, means_bf, x_sq, m_sq, out);
}